// Round 3
// baseline (242.661 us; speedup 1.0000x reference)
//
#include <hip/hip_runtime.h>
#include <math.h>

static constexpr int B_ = 8, L_ = 16, N_ = 256;
static constexpr int NN = N_ * N_;      // 65536
static constexpr int IMGS = B_ * L_;    // 128

__device__ __forceinline__ float2 cmul(float2 a, float2 b) {
    return make_float2(a.x * b.x - a.y * b.y, a.x * b.y + a.y * b.x);
}

// twiddle table: tw[k] = exp(-2*pi*i*k/256), k in [0,128)
__device__ __forceinline__ void twinit(float2* tw, int tid, int nthr) {
    for (int k = tid; k < 128; k += nthr) {
        float ang = -3.14159265358979323846f * (float)k / 128.0f;
        float s, c;
        sincosf(ang, &s, &c);
        tw[k] = make_float2(c, s);
    }
}

// Stockham radix-2 FFT-256, one wave (64 lanes) per row, 2 butterflies/lane/stage.
// Data starts in b0; result ends in b0.
template <bool INV>
__device__ __forceinline__ void fft256_wave(float2* b0, float2* b1,
                                            const float2* tw, int lane) {
    float2* cur = b0;
    float2* oth = b1;
#pragma unroll
    for (int st = 0; st < 8; ++st) {
        int s = 1 << st;
        int m = 128 >> st;   // n/2 with n = 256>>st
#pragma unroll
        for (int r2 = 0; r2 < 2; ++r2) {
            int u = lane + (r2 << 6);
            int q = u & (s - 1);
            int p = u >> st;
            float2 a = cur[q + s * p];
            float2 c = cur[q + s * (p + m)];
            float2 w = tw[p << st];
            if (INV) w.y = -w.y;
            oth[q + 2 * s * p] = make_float2(a.x + c.x, a.y + c.y);
            float2 d = make_float2(a.x - c.x, a.y - c.y);
            oth[q + 2 * s * p + s] = cmul(d, w);
        }
        float2* t = cur; cur = oth; oth = t;
        __syncthreads();
    }
}

// Column-FFT over an 8-column tile in LDS (stride 9 to dodge bank conflicts).
// 256 threads, 4 butterflies/thread/stage. Data starts in b0; ends in b0.
template <bool INV>
__device__ __forceinline__ void fft256_cols8(float2* b0, float2* b1,
                                             const float2* tw, int tid) {
    float2* cur = b0;
    float2* oth = b1;
#pragma unroll
    for (int st = 0; st < 8; ++st) {
        int s = 1 << st;
        int m = 128 >> st;
#pragma unroll
        for (int k = 0; k < 4; ++k) {
            int u = tid + (k << 8);
            int col = u & 7;
            int bf = u >> 3;
            int q = bf & (s - 1);
            int p = bf >> st;
            float2 a = cur[(q + s * p) * 9 + col];
            float2 c = cur[(q + s * (p + m)) * 9 + col];
            float2 w = tw[p << st];
            if (INV) w.y = -w.y;
            oth[(q + 2 * s * p) * 9 + col] = make_float2(a.x + c.x, a.y + c.y);
            float2 d = make_float2(a.x - c.x, a.y - c.y);
            oth[(q + 2 * s * p + s) * 9 + col] = cmul(d, w);
        }
        float2* t = cur; cur = oth; oth = t;
        __syncthreads();
    }
}

// K1: X = mask_l * Z_b, row FFT, write T[b,l,row,:]
__global__ __launch_bounds__(256) void k_rowfft(
    const float* __restrict__ Zre, const float* __restrict__ Zim,
    const float* __restrict__ Mre, const float* __restrict__ Mim,
    float2* __restrict__ T) {
    __shared__ float2 tw[128];
    __shared__ float2 buf[4][2][256];
    int tid = threadIdx.x;
    twinit(tw, tid, 256);
    __syncthreads();

    int wave = tid >> 6, lane = tid & 63;
    int rowg = blockIdx.x * 4 + wave;          // [0, B*L*N)
    int b = rowg >> 12;                        // / (L*N)
    int l = (rowg >> 8) & 15;
    int row = rowg & 255;

    int zbase = (b << 16) + (row << 8);
    int mbase = (l << 16) + (row << 8);
#pragma unroll
    for (int k = 0; k < 4; ++k) {
        int i = lane + (k << 6);
        float2 z = make_float2(Zre[zbase + i], Zim[zbase + i]);
        float2 m = make_float2(Mre[mbase + i], Mim[mbase + i]);
        buf[wave][0][i] = cmul(m, z);
    }
    __syncthreads();

    fft256_wave<false>(&buf[wave][0][0], &buf[wave][1][0], tw, lane);

    float2* outp = T + (((size_t)(b * L_ + l) << 8) + row) * 256;
#pragma unroll
    for (int k = 0; k < 4; ++k) {
        int i = lane + (k << 6);
        outp[i] = buf[wave][0][i];
    }
}

// K2: per (image, 8-column tile): col FFT -> *Ytr -> col IFFT, in place on T.
__global__ __launch_bounds__(256) void k_colpass(
    float2* __restrict__ T, const float* __restrict__ Ytr) {
    __shared__ float2 tw[128];
    __shared__ float2 bA[256 * 9];
    __shared__ float2 bB[256 * 9];
    int tid = threadIdx.x;
    twinit(tw, tid, 256);

    int img = blockIdx.x >> 5;        // [0,128)
    int c0 = (blockIdx.x & 31) << 3;  // column group * 8
    size_t imgBase = (size_t)img << 16;

#pragma unroll
    for (int chunk = 0; chunk < 8; ++chunk) {
        int e = (chunk << 8) + tid;
        int r = e >> 3, c = e & 7;
        bA[r * 9 + c] = T[imgBase + (r << 8) + c0 + c];
    }
    __syncthreads();

    fft256_cols8<false>(bA, bB, tw, tid);

    // multiply by Ytr (elementwise, real)
#pragma unroll
    for (int chunk = 0; chunk < 8; ++chunk) {
        int e = (chunk << 8) + tid;
        int r = e >> 3, c = e & 7;
        float y = Ytr[imgBase + (r << 8) + c0 + c];
        float2 v = bA[r * 9 + c];
        bA[r * 9 + c] = make_float2(v.x * y, v.y * y);
    }
    __syncthreads();

    fft256_cols8<true>(bA, bB, tw, tid);

#pragma unroll
    for (int chunk = 0; chunk < 8; ++chunk) {
        int e = (chunk << 8) + tid;
        int r = e >> 3, c = e & 7;
        T[imgBase + (r << 8) + c0 + c] = bA[r * 9 + c];
    }
}

// K3: row IFFT per (b,row) for each l; accumulate conj(mask_l)*v; scale; -> ATY
__global__ __launch_bounds__(256) void k_rowifft_acc(
    const float2* __restrict__ T,
    const float* __restrict__ Mre, const float* __restrict__ Mim,
    float2* __restrict__ ATY, float scale) {
    __shared__ float2 tw[128];
    __shared__ float2 buf[4][2][256];
    int tid = threadIdx.x;
    twinit(tw, tid, 256);
    __syncthreads();

    int wave = tid >> 6, lane = tid & 63;
    int rowg = blockIdx.x * 4 + wave;   // [0, B*N)
    int b = rowg >> 8;
    int row = rowg & 255;

    float2 acc[4];
#pragma unroll
    for (int k = 0; k < 4; ++k) acc[k] = make_float2(0.f, 0.f);

    for (int l = 0; l < L_; ++l) {
        const float2* src = T + (((size_t)(b * L_ + l) << 8) + row) * 256;
#pragma unroll
        for (int k = 0; k < 4; ++k) {
            int i = lane + (k << 6);
            buf[wave][0][i] = src[i];
        }
        __syncthreads();

        fft256_wave<true>(&buf[wave][0][0], &buf[wave][1][0], tw, lane);

        int mbase = (l << 16) + (row << 8);
#pragma unroll
        for (int k = 0; k < 4; ++k) {
            int i = lane + (k << 6);
            float2 v = buf[wave][0][i];
            float mr = Mre[mbase + i], mi = Mim[mbase + i];
            acc[k].x += mr * v.x + mi * v.y;   // conj(m) * v
            acc[k].y += mr * v.y - mi * v.x;
        }
        __syncthreads();
    }

    int obase = (b << 16) + (row << 8);
#pragma unroll
    for (int k = 0; k < 4; ++k) {
        int i = lane + (k << 6);
        ATY[obase + i] = make_float2(acc[k].x * scale, acc[k].y * scale);
    }
}

// K4a: conv 5x5 (SAME, zero pad, correlation) + bias on re & im for an
// 8-row slice of one image; write Zc; partial sum-of-squares -> ssq_part.
__global__ __launch_bounds__(256) void k_conv(
    const float2* __restrict__ ATY, const float* __restrict__ W,
    const float* __restrict__ bptr, float2* __restrict__ Zc,
    float* __restrict__ ssq_part) {
    __shared__ float wsh[25];
    __shared__ float red[256];
    int slice = blockIdx.x & 31;      // 8-row slice
    int b = blockIdx.x >> 5;
    int tid = threadIdx.x;
    if (tid < 25) wsh[tid] = W[tid];
    __syncthreads();
    float bias = bptr[0];

    const float2* img = ATY + ((size_t)b << 16);
    float2* zc = Zc + ((size_t)b << 16);
    int row0 = slice << 3;
    float ssq = 0.f;
#pragma unroll 1
    for (int k = 0; k < 8; ++k) {
        int pix = (row0 << 8) + (k << 8) + tid;
        int h = pix >> 8, w = pix & 255;
        float ar = bias, ai = bias;
#pragma unroll
        for (int kh = 0; kh < 5; ++kh) {
            int hh = h + kh - 2;
            if (hh < 0 || hh > 255) continue;
#pragma unroll
            for (int kw = 0; kw < 5; ++kw) {
                int ww = w + kw - 2;
                if (ww < 0 || ww > 255) continue;
                float wgt = wsh[kh * 5 + kw];
                float2 v = img[(hh << 8) + ww];
                ar = fmaf(v.x, wgt, ar);
                ai = fmaf(v.y, wgt, ai);
            }
        }
        zc[pix] = make_float2(ar, ai);
        ssq = fmaf(ar, ar, fmaf(ai, ai, ssq));
    }
    red[tid] = ssq;
    __syncthreads();
#pragma unroll
    for (int off = 128; off > 0; off >>= 1) {
        if (tid < off) red[tid] += red[tid + off];
        __syncthreads();
    }
    if (tid == 0) ssq_part[blockIdx.x] = red[0];
}

// K4b: sum the 32 partials for image b, normalize 4096-pixel slice, write out.
__global__ __launch_bounds__(256) void k_norm(
    const float2* __restrict__ Zc, const float* __restrict__ ssq_part,
    float* __restrict__ out) {
    __shared__ float red[32];
    int slice = blockIdx.x & 15;      // 16 slices of 4096 pixels
    int b = blockIdx.x >> 4;
    int tid = threadIdx.x;
    if (tid < 32) red[tid] = ssq_part[(b << 5) + tid];
    __syncthreads();
    if (tid == 0) {
        float s = 0.f;
#pragma unroll
        for (int i = 0; i < 32; ++i) s += red[i];
        red[0] = s;
    }
    __syncthreads();
    float invf = 1.0f / sqrtf(red[0]);

    const float2* zc = Zc + ((size_t)b << 16);
    float* outRe = out + ((size_t)b << 16);
    float* outIm = out + ((size_t)(B_ + b) << 16);
#pragma unroll
    for (int k = 0; k < 16; ++k) {
        int pix = (slice << 12) + (k << 8) + tid;
        float2 v = zc[pix];
        outRe[pix] = v.x * invf;
        outIm[pix] = v.y * invf;
    }
}

extern "C" void kernel_launch(void* const* d_in, const int* in_sizes, int n_in,
                              void* d_out, int out_size, void* d_ws, size_t ws_size,
                              hipStream_t stream) {
    const float* Zre = (const float*)d_in[0];
    const float* Zim = (const float*)d_in[1];
    const float* Mre = (const float*)d_in[2];
    const float* Mim = (const float*)d_in[3];
    const float* Ytr = (const float*)d_in[4];
    const float* W   = (const float*)d_in[5];
    const float* bia = (const float*)d_in[6];
    float* out = (float*)d_out;

    float2* T   = (float2*)d_ws;                 // B*L*N*N complex (64 MB)
    float2* ATY = T + (size_t)IMGS * NN;         // B*N*N complex (4 MB)
    float*  ssq = (float*)(ATY + (size_t)B_ * NN);   // 256 floats
    float2* Zc  = T;                             // alias: T dead after K3

    // ifft2 scale (1/65536) * div (M*R = 1048576 * 174763)
    const float scale = 1.0f / (float)(65536.0 * 1048576.0 * 174763.0);

    k_rowfft<<<dim3(IMGS * N_ / 4), dim3(256), 0, stream>>>(Zre, Zim, Mre, Mim, T);
    k_colpass<<<dim3(IMGS * 32), dim3(256), 0, stream>>>(T, Ytr);
    k_rowifft_acc<<<dim3(B_ * N_ / 4), dim3(256), 0, stream>>>(T, Mre, Mim, ATY, scale);
    k_conv<<<dim3(B_ * 32), dim3(256), 0, stream>>>(ATY, W, bia, Zc, ssq);
    k_norm<<<dim3(B_ * 16), dim3(256), 0, stream>>>(Zc, ssq, out);
}

// Round 4
// 206.430 us; speedup vs baseline: 1.1755x; 1.1755x over previous
//
#include <hip/hip_runtime.h>
#include <math.h>

static constexpr int B_ = 8, L_ = 16, N_ = 256;
static constexpr int NN = N_ * N_;      // 65536
static constexpr int IMGS = B_ * L_;    // 128

__device__ __forceinline__ float2 cmul(float2 a, float2 b) {
    return make_float2(a.x * b.x - a.y * b.y, a.x * b.y + a.y * b.x);
}

// LDS swizzle: spreads every radix-4 Stockham read/write pattern to the
// 4-lane/bank-pair minimum (derived per stage; bijective on [0,256)).
__device__ __forceinline__ int sig(int e) { return e ^ ((e >> 4) & 0xF); }

// tw[n] = exp(-2*pi*i*n/256), n in [0,192)  (max index used: 3*63 = 189)
__device__ __forceinline__ void twinit192(float2* tw, int tid) {
    if (tid < 192) {
        float ang = -3.14159265358979323846f * (float)tid / 128.0f;
        float s, c;
        sincosf(ang, &s, &c);
        tw[tid] = make_float2(c, s);
    }
}

template <bool INV>
__device__ __forceinline__ void dft4(const float2* x, float2* X) {
    float2 t0 = make_float2(x[0].x + x[2].x, x[0].y + x[2].y);
    float2 t1 = make_float2(x[0].x - x[2].x, x[0].y - x[2].y);
    float2 t2 = make_float2(x[1].x + x[3].x, x[1].y + x[3].y);
    float2 t3 = make_float2(x[1].x - x[3].x, x[1].y - x[3].y);
    X[0] = make_float2(t0.x + t2.x, t0.y + t2.y);
    X[2] = make_float2(t0.x - t2.x, t0.y - t2.y);
    if (!INV) {                                  // w4 = -i
        X[1] = make_float2(t1.x + t3.y, t1.y - t3.x);
        X[3] = make_float2(t1.x - t3.y, t1.y + t3.x);
    } else {                                     // w4 = +i
        X[1] = make_float2(t1.x - t3.y, t1.y + t3.x);
        X[3] = make_float2(t1.x + t3.y, t1.y - t3.x);
    }
}

// Radix-4 Stockham FFT-256, one wave per row, 1 butterfly/lane/stage.
// Entry: r[j] = x[lane + 64j].  Exit: r[k] = X[lane + 64k].
// 3 LDS exchanges (st0->b0, st1->b1, st2->b0), 3 barriers total.
template <bool INV>
__device__ __forceinline__ void fft256_r4(float2* r, float2* b0, float2* b1,
                                          const float2* tw, int lane) {
#pragma unroll
    for (int st = 0; st < 4; ++st) {
        float2 X[4];
        dft4<INV>(r, X);
        if (st < 3) {
            int sh = 2 * st, s = 1 << sh;
            int ps = (lane >> sh) << sh;      // p*s
            float2 w1 = tw[ps], w2 = tw[2 * ps], w3 = tw[3 * ps];
            if (INV) { w1.y = -w1.y; w2.y = -w2.y; w3.y = -w3.y; }
            X[1] = cmul(X[1], w1);
            X[2] = cmul(X[2], w2);
            X[3] = cmul(X[3], w3);
            float2* buf = (st & 1) ? b1 : b0;
            int base = lane + 3 * ps;         // q + 4*s*p
#pragma unroll
            for (int k = 0; k < 4; ++k) buf[sig(base + k * s)] = X[k];
            __syncthreads();
#pragma unroll
            for (int j = 0; j < 4; ++j) r[j] = buf[sig(lane + 64 * j)];
        } else {
#pragma unroll
            for (int k = 0; k < 4; ++k) r[k] = X[k];
        }
    }
}

// Column-FFT variant: 256 threads, 8 columns, 2 butterflies/thread (bf = s2, s2+32).
// LDS index: col*256 + (sig(e)^col).  Entry/exit reg layout: r[h][j] = x[(s2+32h)+64j].
template <bool INV>
__device__ __forceinline__ void fft256_r4_col(float2 (*r)[4], float2* b0, float2* b1,
                                              const float2* tw, int s2, int c) {
#pragma unroll
    for (int st = 0; st < 4; ++st) {
        float2 X[2][4];
#pragma unroll
        for (int h = 0; h < 2; ++h) dft4<INV>(r[h], X[h]);
        if (st < 3) {
            int sh = 2 * st, s = 1 << sh;
            float2* buf = (st & 1) ? b1 : b0;
#pragma unroll
            for (int h = 0; h < 2; ++h) {
                int bf = s2 + 32 * h;
                int ps = (bf >> sh) << sh;
                float2 w1 = tw[ps], w2 = tw[2 * ps], w3 = tw[3 * ps];
                if (INV) { w1.y = -w1.y; w2.y = -w2.y; w3.y = -w3.y; }
                X[h][1] = cmul(X[h][1], w1);
                X[h][2] = cmul(X[h][2], w2);
                X[h][3] = cmul(X[h][3], w3);
                int base = bf + 3 * ps;
#pragma unroll
                for (int k = 0; k < 4; ++k)
                    buf[(c << 8) + (sig(base + k * s) ^ c)] = X[h][k];
            }
            __syncthreads();
#pragma unroll
            for (int h = 0; h < 2; ++h)
#pragma unroll
                for (int j = 0; j < 4; ++j)
                    r[h][j] = buf[(c << 8) + (sig(s2 + 32 * h + 64 * j) ^ c)];
        } else {
#pragma unroll
            for (int h = 0; h < 2; ++h)
#pragma unroll
                for (int k = 0; k < 4; ++k) r[h][k] = X[h][k];
        }
    }
}

// K1: X = mask_l * Z_b, row FFT, write T[b,l,row,:]
__global__ __launch_bounds__(256) void k_rowfft(
    const float* __restrict__ Zre, const float* __restrict__ Zim,
    const float* __restrict__ Mre, const float* __restrict__ Mim,
    float2* __restrict__ T) {
    __shared__ float2 tw[192];
    __shared__ float2 xch[4][2][256];
    int tid = threadIdx.x;
    twinit192(tw, tid);
    __syncthreads();

    int wave = tid >> 6, lane = tid & 63;
    int rowg = blockIdx.x * 4 + wave;          // [0, B*L*N)
    int b = rowg >> 12, l = (rowg >> 8) & 15, row = rowg & 255;

    int zbase = (b << 16) + (row << 8);
    int mbase = (l << 16) + (row << 8);
    float2 r[4];
#pragma unroll
    for (int j = 0; j < 4; ++j) {
        int i = lane + 64 * j;
        float2 z = make_float2(Zre[zbase + i], Zim[zbase + i]);
        float2 m = make_float2(Mre[mbase + i], Mim[mbase + i]);
        r[j] = cmul(m, z);
    }
    fft256_r4<false>(r, &xch[wave][0][0], &xch[wave][1][0], tw, lane);

    float2* outp = T + (((size_t)(b * 16 + l)) << 16) + (row << 8);
#pragma unroll
    for (int k = 0; k < 4; ++k) outp[lane + 64 * k] = r[k];
}

// K2: per (image, 8-col tile): col FFT -> *Ytr -> col IFFT, in place on T.
// No LDS traffic between the two FFTs (reg layouts match).
__global__ __launch_bounds__(256) void k_colpass(
    float2* __restrict__ T, const float* __restrict__ Ytr) {
    __shared__ float2 tw[192];
    __shared__ float2 cb0[2048];
    __shared__ float2 cb1[2048];
    int tid = threadIdx.x;
    twinit192(tw, tid);
    __syncthreads();

    int img = blockIdx.x >> 5;
    int c0 = (blockIdx.x & 31) << 3;
    size_t base = ((size_t)img << 16) + c0;
    int c = tid & 7, s2 = tid >> 3;

    float2 r[2][4];
#pragma unroll
    for (int h = 0; h < 2; ++h)
#pragma unroll
        for (int j = 0; j < 4; ++j)
            r[h][j] = T[base + ((s2 + 32 * h + 64 * j) << 8) + c];

    fft256_r4_col<false>(r, cb0, cb1, tw, s2, c);

#pragma unroll
    for (int h = 0; h < 2; ++h)
#pragma unroll
        for (int k = 0; k < 4; ++k) {
            float y = Ytr[base + ((s2 + 32 * h + 64 * k) << 8) + c];
            r[h][k].x *= y;
            r[h][k].y *= y;
        }

    fft256_r4_col<true>(r, cb1, cb0, tw, s2, c);  // swapped bufs: WAR-safe

#pragma unroll
    for (int h = 0; h < 2; ++h)
#pragma unroll
        for (int k = 0; k < 4; ++k)
            T[base + ((s2 + 32 * h + 64 * k) << 8) + c] = r[h][k];
}

// K3: row IFFT for 4 of the 16 l's (blockIdx.y = l-group); accumulate
// conj(mask_l)*v in regs; atomically add scaled partials into ATY.
__global__ __launch_bounds__(256) void k_rowifft_acc(
    const float2* __restrict__ T,
    const float* __restrict__ Mre, const float* __restrict__ Mim,
    float2* __restrict__ ATY, float scale) {
    __shared__ float2 tw[192];
    __shared__ float2 xch[4][2][256];
    int tid = threadIdx.x;
    twinit192(tw, tid);
    __syncthreads();

    int wave = tid >> 6, lane = tid & 63;
    int rowg = blockIdx.x * 4 + wave;   // [0, B*N)
    int b = rowg >> 8, row = rowg & 255;
    int g = blockIdx.y;                 // l-group [0,4)

    float2 acc[4];
#pragma unroll
    for (int k = 0; k < 4; ++k) acc[k] = make_float2(0.f, 0.f);

#pragma unroll 1
    for (int li = 0; li < 4; ++li) {
        int l = (g << 2) + li;
        const float2* src = T + (((size_t)(b * 16 + l)) << 16) + (row << 8);
        float2 r[4];
#pragma unroll
        for (int j = 0; j < 4; ++j) r[j] = src[lane + 64 * j];
        // alternate buffer order per li -> no extra barrier needed
        float2* ba = &xch[wave][li & 1][0];
        float2* bb = &xch[wave][(li & 1) ^ 1][0];
        fft256_r4<true>(r, ba, bb, tw, lane);
        int mbase = (l << 16) + (row << 8);
#pragma unroll
        for (int k = 0; k < 4; ++k) {
            int i = lane + 64 * k;
            float mr = Mre[mbase + i], mi = Mim[mbase + i];
            acc[k].x += mr * r[k].x + mi * r[k].y;   // conj(m) * v
            acc[k].y += mr * r[k].y - mi * r[k].x;
        }
    }

    float* dst = (float*)(ATY + ((size_t)b << 16) + (row << 8));
#pragma unroll
    for (int k = 0; k < 4; ++k) {
        int i = lane + 64 * k;
        atomicAdd(dst + 2 * i,     acc[k].x * scale);
        atomicAdd(dst + 2 * i + 1, acc[k].y * scale);
    }
}

// K4a: 5x5 correlation (SAME, zero pad) + bias on re & im, 4-row slices.
__global__ __launch_bounds__(256) void k_conv(
    const float2* __restrict__ ATY, const float* __restrict__ W,
    const float* __restrict__ bptr, float2* __restrict__ Zc,
    float* __restrict__ ssq_part) {
    __shared__ float wsh[25];
    __shared__ float red[256];
    int slice = blockIdx.x & 63;      // 64 slices of 4 rows
    int b = blockIdx.x >> 6;
    int tid = threadIdx.x;
    if (tid < 25) wsh[tid] = W[tid];
    __syncthreads();
    float bias = bptr[0];

    const float2* img = ATY + ((size_t)b << 16);
    float2* zc = Zc + ((size_t)b << 16);
    int row0 = slice << 2;
    float ssq = 0.f;
#pragma unroll 1
    for (int k = 0; k < 4; ++k) {
        int h = row0 + k, w = tid;
        float ar = bias, ai = bias;
#pragma unroll
        for (int kh = 0; kh < 5; ++kh) {
            int hh = h + kh - 2;
            if (hh < 0 || hh > 255) continue;
#pragma unroll
            for (int kw = 0; kw < 5; ++kw) {
                int ww = w + kw - 2;
                if (ww < 0 || ww > 255) continue;
                float wgt = wsh[kh * 5 + kw];
                float2 v = img[(hh << 8) + ww];
                ar = fmaf(v.x, wgt, ar);
                ai = fmaf(v.y, wgt, ai);
            }
        }
        zc[(h << 8) + w] = make_float2(ar, ai);
        ssq = fmaf(ar, ar, fmaf(ai, ai, ssq));
    }
    red[tid] = ssq;
    __syncthreads();
#pragma unroll
    for (int off = 128; off > 0; off >>= 1) {
        if (tid < off) red[tid] += red[tid + off];
        __syncthreads();
    }
    if (tid == 0) ssq_part[blockIdx.x] = red[0];
}

// K4b: sum 64 partials for image b, normalize 4096-pixel slice, write out.
__global__ __launch_bounds__(256) void k_norm(
    const float2* __restrict__ Zc, const float* __restrict__ ssq_part,
    float* __restrict__ out) {
    __shared__ float red[64];
    int slice = blockIdx.x & 15;
    int b = blockIdx.x >> 4;
    int tid = threadIdx.x;
    if (tid < 64) red[tid] = ssq_part[(b << 6) + tid];
    __syncthreads();
    if (tid == 0) {
        float s = 0.f;
#pragma unroll
        for (int i = 0; i < 64; ++i) s += red[i];
        red[0] = s;
    }
    __syncthreads();
    float invf = 1.0f / sqrtf(red[0]);

    const float2* zc = Zc + ((size_t)b << 16);
    float* outRe = out + ((size_t)b << 16);
    float* outIm = out + ((size_t)(B_ + b) << 16);
#pragma unroll
    for (int k = 0; k < 16; ++k) {
        int pix = (slice << 12) + (k << 8) + tid;
        float2 v = zc[pix];
        outRe[pix] = v.x * invf;
        outIm[pix] = v.y * invf;
    }
}

extern "C" void kernel_launch(void* const* d_in, const int* in_sizes, int n_in,
                              void* d_out, int out_size, void* d_ws, size_t ws_size,
                              hipStream_t stream) {
    const float* Zre = (const float*)d_in[0];
    const float* Zim = (const float*)d_in[1];
    const float* Mre = (const float*)d_in[2];
    const float* Mim = (const float*)d_in[3];
    const float* Ytr = (const float*)d_in[4];
    const float* W   = (const float*)d_in[5];
    const float* bia = (const float*)d_in[6];
    float* out = (float*)d_out;

    float2* T   = (float2*)d_ws;                 // B*L*N*N complex (67 MB)
    float2* ATY = T + (size_t)IMGS * NN;         // B*N*N complex (4.2 MB)
    float*  ssq = (float*)(ATY + (size_t)B_ * NN);   // 512 floats
    float2* Zc  = T;                             // alias: T dead after K3

    // ifft2 scale (1/65536) * div (M*R = 1048576 * 174763)
    const float scale = 1.0f / (float)(65536.0 * 1048576.0 * 174763.0);

    hipMemsetAsync(ATY, 0, (size_t)B_ * NN * sizeof(float2), stream);
    k_rowfft<<<dim3(IMGS * N_ / 4), dim3(256), 0, stream>>>(Zre, Zim, Mre, Mim, T);
    k_colpass<<<dim3(IMGS * 32), dim3(256), 0, stream>>>(T, Ytr);
    k_rowifft_acc<<<dim3(B_ * N_ / 4, 4), dim3(256), 0, stream>>>(T, Mre, Mim, ATY, scale);
    k_conv<<<dim3(B_ * 64), dim3(256), 0, stream>>>(ATY, W, bia, Zc, ssq);
    k_norm<<<dim3(B_ * 16), dim3(256), 0, stream>>>(Zc, ssq, out);
}

// Round 6
// 183.729 us; speedup vs baseline: 1.3208x; 1.1236x over previous
//
#include <hip/hip_runtime.h>
#include <math.h>

static constexpr int B_ = 8, L_ = 16, N_ = 256;
static constexpr int NN = N_ * N_;      // 65536
static constexpr int IMGS = B_ * L_;    // 128

__device__ __forceinline__ float2 cmul(float2 a, float2 b) {
    return make_float2(a.x * b.x - a.y * b.y, a.x * b.y + a.y * b.x);
}

// tw[n] = exp(-2*pi*i*n/256), n in [0,256)
__device__ __forceinline__ void twinit(float2* tw, int tid) {
    float ang = -3.14159265358979323846f * (float)tid / 128.0f;
    float s, c;
    sincosf(ang, &s, &c);
    tw[tid] = make_float2(c, s);
}

template <bool INV>
__device__ __forceinline__ void dft4(const float2* x, float2* X) {
    float2 t0 = make_float2(x[0].x + x[2].x, x[0].y + x[2].y);
    float2 t1 = make_float2(x[0].x - x[2].x, x[0].y - x[2].y);
    float2 t2 = make_float2(x[1].x + x[3].x, x[1].y + x[3].y);
    float2 t3 = make_float2(x[1].x - x[3].x, x[1].y - x[3].y);
    X[0] = make_float2(t0.x + t2.x, t0.y + t2.y);
    X[2] = make_float2(t0.x - t2.x, t0.y - t2.y);
    if (!INV) {                                  // w4 = -i
        X[1] = make_float2(t1.x + t3.y, t1.y - t3.x);
        X[3] = make_float2(t1.x - t3.y, t1.y + t3.x);
    } else {                                     // w4 = +i
        X[1] = make_float2(t1.x - t3.y, t1.y + t3.x);
        X[3] = make_float2(t1.x + t3.y, t1.y - t3.x);
    }
}

// v * exp(-2*pi*i*k/16) (fwd) / conj (inv); k in {0,1,2,3,4,6,9} (compile-time)
template <bool INV>
__device__ __forceinline__ float2 w16mul(float2 v, int k) {
    constexpr float C = 0.92387953251128674f, S = 0.38268343236508978f,
                    R = 0.70710678118654746f;
    float re = 1.f, im = 0.f;
    switch (k) {
        case 0: return v;
        case 1: re = C;  im = -S; break;
        case 2: re = R;  im = -R; break;
        case 3: re = S;  im = -C; break;
        case 4: re = 0.f; im = -1.f; break;
        case 6: re = -R; im = -R; break;
        case 9: re = -C; im = S;  break;
    }
    if (INV) im = -im;
    return cmul(v, make_float2(re, im));
}

// 16-point DFT in registers: y[k] = sum_n x[n] w16^{nk} (conj for INV).
// Two radix-4 stages; all twiddles compile-time constants.
template <bool INV>
__device__ __forceinline__ void dft16(const float2* x, float2* y) {
    float2 A[4][4];
#pragma unroll
    for (int n0 = 0; n0 < 4; ++n0) {
        float2 in[4] = {x[n0], x[n0 + 4], x[n0 + 8], x[n0 + 12]};
        dft4<INV>(in, A[n0]);
    }
#pragma unroll
    for (int k1 = 0; k1 < 4; ++k1) {
#pragma unroll
        for (int n0 = 1; n0 < 4; ++n0) A[n0][k1] = w16mul<INV>(A[n0][k1], n0 * k1);
        float2 in[4] = {A[0][k1], A[1][k1], A[2][k1], A[3][k1]};
        float2 o[4];
        dft4<INV>(in, o);
#pragma unroll
        for (int k0 = 0; k0 < 4; ++k0) y[k1 + 4 * k0] = o[k0];
    }
}

// Radix-16 "4-step" FFT-256. 16 threads per FFT (sub-index a), each holding
// r[c] = x[a + 16c]. One LDS transpose (padded: t*17+a, group stride 273 ->
// every phase spreads 64 lanes over all 16 bank-pairs). Exit: r[d] = X[a+16d].
// Caller must __syncthreads() before the next write to xg (WAR).
template <bool INV>
__device__ __forceinline__ void fft256_r16(float2* r, float2* xg,
                                           const float2* tw, int a) {
    float2 y[16];
    dft16<INV>(r, y);                         // Y_a[t]
#pragma unroll
    for (int t = 1; t < 16; ++t) {            // outer twiddle w256^{a*t}
        float2 w = tw[a * t];
        if (INV) w.y = -w.y;
        y[t] = cmul(y[t], w);
    }
#pragma unroll
    for (int t = 0; t < 16; ++t) xg[t * 17 + a] = y[t];
    __syncthreads();
#pragma unroll
    for (int aa = 0; aa < 16; ++aa) r[aa] = xg[a * 17 + aa];  // this thread: t'=a
    dft16<INV>(r, y);                         // X[t' + 16d]
#pragma unroll
    for (int i = 0; i < 16; ++i) r[i] = y[i];
}

// K1: X = mask_l * Z_b, row FFT, write T[b,l,row,:].  16 rows per block.
__global__ __launch_bounds__(256) void k_rowfft(
    const float* __restrict__ Zre, const float* __restrict__ Zim,
    const float* __restrict__ Mre, const float* __restrict__ Mim,
    float2* __restrict__ T) {
    __shared__ float2 tw[256];
    __shared__ float2 xch[4368];              // 16 groups * 273
    int tid = threadIdx.x;
    twinit(tw, tid);
    __syncthreads();

    int g = tid >> 4, a = tid & 15;
    int rowg = blockIdx.x * 16 + g;           // [0, B*L*N)
    int b = rowg >> 12, l = (rowg >> 8) & 15, row = rowg & 255;

    int zbase = (b << 16) + (row << 8);
    int mbase = (l << 16) + (row << 8);
    float2 r[16];
#pragma unroll
    for (int c = 0; c < 16; ++c) {
        int i = a + 16 * c;
        float2 z = make_float2(Zre[zbase + i], Zim[zbase + i]);
        float2 m = make_float2(Mre[mbase + i], Mim[mbase + i]);
        r[c] = cmul(m, z);
    }
    fft256_r16<false>(r, &xch[g * 273], tw, a);

    float2* outp = T + (((size_t)(b * 16 + l)) << 16) + (row << 8);
#pragma unroll
    for (int d = 0; d < 16; ++d) outp[a + 16 * d] = r[d];
}

// K2: per (image, 16-col tile): col FFT -> *Ytr -> col IFFT, in place on T.
// Zero LDS traffic between the two FFTs (reg layouts match).
__global__ __launch_bounds__(256) void k_colpass(
    float2* __restrict__ T, const float* __restrict__ Ytr) {
    __shared__ float2 tw[256];
    __shared__ float2 xch[4368];
    int tid = threadIdx.x;
    twinit(tw, tid);
    __syncthreads();

    int img = blockIdx.x >> 4;
    int c0 = (blockIdx.x & 15) << 4;
    int c = tid & 15, a = tid >> 4;
    size_t base = ((size_t)img << 16) + c0 + c;

    float2 r[16];
#pragma unroll
    for (int cc = 0; cc < 16; ++cc) r[cc] = T[base + ((a + 16 * cc) << 8)];

    fft256_r16<false>(r, &xch[c * 273], tw, a);   // r[d] = X[a + 16d]

#pragma unroll
    for (int d = 0; d < 16; ++d) {
        float y = Ytr[base + ((a + 16 * d) << 8)];
        r[d].x *= y;
        r[d].y *= y;
    }
    __syncthreads();                               // WAR on xch

    fft256_r16<true>(r, &xch[c * 273], tw, a);

#pragma unroll
    for (int d = 0; d < 16; ++d) T[base + ((a + 16 * d) << 8)] = r[d];
}

// K3: row IFFT for 4 of 16 l's (blockIdx.y = group); accumulate conj(mask)*v
// in registers; write scaled partial into dead T slot (image b*16 + 4*group).
__global__ __launch_bounds__(256) void k_rowifft_acc(
    float2* __restrict__ T,
    const float* __restrict__ Mre, const float* __restrict__ Mim,
    float scale) {
    __shared__ float2 tw[256];
    __shared__ float2 xch[4368];
    int tid = threadIdx.x;
    twinit(tw, tid);
    __syncthreads();

    int g = tid >> 4, a = tid & 15;
    int rowg = blockIdx.x * 16 + g;           // [0, B*N)
    int b = rowg >> 8, row = rowg & 255;
    int lg = blockIdx.y;                      // l-group [0,4)

    float2 acc[16];
#pragma unroll
    for (int k = 0; k < 16; ++k) acc[k] = make_float2(0.f, 0.f);

#pragma unroll 1
    for (int li = 0; li < 4; ++li) {
        int l = (lg << 2) + li;
        const float2* src = T + (((size_t)(b * 16 + l)) << 16) + (row << 8);
        float2 r[16];
#pragma unroll
        for (int c = 0; c < 16; ++c) r[c] = src[a + 16 * c];
        __syncthreads();                      // WAR on xch vs previous iter
        fft256_r16<true>(r, &xch[g * 273], tw, a);
        int mbase = (l << 16) + (row << 8);
#pragma unroll
        for (int d = 0; d < 16; ++d) {
            int i = a + 16 * d;
            float mr = Mre[mbase + i], mi = Mim[mbase + i];
            acc[d].x += mr * r[d].x + mi * r[d].y;   // conj(m) * v
            acc[d].y += mr * r[d].y - mi * r[d].x;
        }
    }

    float2* dst = T + (((size_t)(b * 16 + (lg << 2))) << 16) + (row << 8);
#pragma unroll
    for (int d = 0; d < 16; ++d)
        dst[a + 16 * d] = make_float2(acc[d].x * scale, acc[d].y * scale);
}

// K3b: ATY = sum of the 4 partials sitting in T images b*16 + {0,4,8,12}.
__global__ __launch_bounds__(256) void k_sum4(
    const float2* __restrict__ T, float2* __restrict__ ATY) {
    int i = blockIdx.x * 2048 + threadIdx.x;
#pragma unroll
    for (int k = 0; k < 8; ++k) {
        int p = i + (k << 8);
        int b = p >> 16, pix = p & 65535;
        size_t s0 = (((size_t)b << 4) << 16) + pix;
        float2 v0 = T[s0];
        float2 v1 = T[s0 + ((size_t)4 << 16)];
        float2 v2 = T[s0 + ((size_t)8 << 16)];
        float2 v3 = T[s0 + ((size_t)12 << 16)];
        ATY[p] = make_float2(v0.x + v1.x + v2.x + v3.x,
                             v0.y + v1.y + v2.y + v3.y);
    }
}

// K4a: 5x5 correlation (SAME, zero pad) + bias on re & im, 4-row slices.
__global__ __launch_bounds__(256) void k_conv(
    const float2* __restrict__ ATY, const float* __restrict__ W,
    const float* __restrict__ bptr, float2* __restrict__ Zc,
    float* __restrict__ ssq_part) {
    __shared__ float wsh[25];
    __shared__ float red[256];
    int slice = blockIdx.x & 63;      // 64 slices of 4 rows
    int b = blockIdx.x >> 6;
    int tid = threadIdx.x;
    if (tid < 25) wsh[tid] = W[tid];
    __syncthreads();
    float bias = bptr[0];

    const float2* img = ATY + ((size_t)b << 16);
    float2* zc = Zc + ((size_t)b << 16);
    int row0 = slice << 2;
    float ssq = 0.f;
#pragma unroll 1
    for (int k = 0; k < 4; ++k) {
        int h = row0 + k, w = tid;
        float ar = bias, ai = bias;
#pragma unroll
        for (int kh = 0; kh < 5; ++kh) {
            int hh = h + kh - 2;
            if (hh < 0 || hh > 255) continue;
#pragma unroll
            for (int kw = 0; kw < 5; ++kw) {
                int ww = w + kw - 2;
                if (ww < 0 || ww > 255) continue;
                float wgt = wsh[kh * 5 + kw];
                float2 v = img[(hh << 8) + ww];
                ar = fmaf(v.x, wgt, ar);
                ai = fmaf(v.y, wgt, ai);
            }
        }
        zc[(h << 8) + w] = make_float2(ar, ai);
        ssq = fmaf(ar, ar, fmaf(ai, ai, ssq));
    }
    red[tid] = ssq;
    __syncthreads();
#pragma unroll
    for (int off = 128; off > 0; off >>= 1) {
        if (tid < off) red[tid] += red[tid + off];
        __syncthreads();
    }
    if (tid == 0) ssq_part[blockIdx.x] = red[0];
}

// K4b: sum 64 partials for image b, normalize 4096-pixel slice, write out.
__global__ __launch_bounds__(256) void k_norm(
    const float2* __restrict__ Zc, const float* __restrict__ ssq_part,
    float* __restrict__ out) {
    __shared__ float red[64];
    int slice = blockIdx.x & 15;
    int b = blockIdx.x >> 4;
    int tid = threadIdx.x;
    if (tid < 64) red[tid] = ssq_part[(b << 6) + tid];
    __syncthreads();
    if (tid == 0) {
        float s = 0.f;
#pragma unroll
        for (int i = 0; i < 64; ++i) s += red[i];
        red[0] = s;
    }
    __syncthreads();
    float invf = 1.0f / sqrtf(red[0]);

    const float2* zc = Zc + ((size_t)b << 16);
    float* outRe = out + ((size_t)b << 16);
    float* outIm = out + ((size_t)(B_ + b) << 16);
#pragma unroll
    for (int k = 0; k < 16; ++k) {
        int pix = (slice << 12) + (k << 8) + tid;
        float2 v = zc[pix];
        outRe[pix] = v.x * invf;
        outIm[pix] = v.y * invf;
    }
}

extern "C" void kernel_launch(void* const* d_in, const int* in_sizes, int n_in,
                              void* d_out, int out_size, void* d_ws, size_t ws_size,
                              hipStream_t stream) {
    const float* Zre = (const float*)d_in[0];
    const float* Zim = (const float*)d_in[1];
    const float* Mre = (const float*)d_in[2];
    const float* Mim = (const float*)d_in[3];
    const float* Ytr = (const float*)d_in[4];
    const float* W   = (const float*)d_in[5];
    const float* bia = (const float*)d_in[6];
    float* out = (float*)d_out;

    float2* T   = (float2*)d_ws;                 // B*L*N*N complex (67 MB)
    float2* ATY = T + (size_t)IMGS * NN;         // B*N*N complex (4.2 MB)
    float2* Zc  = ATY + (size_t)B_ * NN;         // B*N*N complex (4.2 MB)
    float*  ssq = (float*)(Zc + (size_t)B_ * NN);    // 512 floats
    // total 75.6 MB (= round-0 proven footprint)

    // ifft2 scale (1/65536) * div (M*R = 1048576 * 174763)
    const float scale = 1.0f / (float)(65536.0 * 1048576.0 * 174763.0);

    k_rowfft<<<dim3(IMGS * N_ / 16), dim3(256), 0, stream>>>(Zre, Zim, Mre, Mim, T);
    k_colpass<<<dim3(IMGS * 16), dim3(256), 0, stream>>>(T, Ytr);
    k_rowifft_acc<<<dim3(B_ * N_ / 16, 4), dim3(256), 0, stream>>>(T, Mre, Mim, scale);
    k_sum4<<<dim3(256), dim3(256), 0, stream>>>(T, ATY);
    k_conv<<<dim3(B_ * 64), dim3(256), 0, stream>>>(ATY, W, bia, Zc, ssq);
    k_norm<<<dim3(B_ * 16), dim3(256), 0, stream>>>(Zc, ssq, out);
}

// Round 11
// 172.274 us; speedup vs baseline: 1.4086x; 1.0665x over previous
//
#include <hip/hip_runtime.h>
#include <hip/hip_fp16.h>
#include <math.h>

static constexpr int B_ = 8, L_ = 16, N_ = 256;
static constexpr int NN = N_ * N_;      // 65536
static constexpr int IMGS = B_ * L_;    // 128

__device__ __forceinline__ float2 cmul(float2 a, float2 b) {
    return make_float2(a.x * b.x - a.y * b.y, a.x * b.y + a.y * b.x);
}

// tw[n] = exp(-2*pi*i*n/256), n in [0,256)
__device__ __forceinline__ void twinit(float2* tw, int tid) {
    float ang = -3.14159265358979323846f * (float)tid / 128.0f;
    float s, c;
    sincosf(ang, &s, &c);
    tw[tid] = make_float2(c, s);
}

template <bool INV>
__device__ __forceinline__ void dft4(const float2* x, float2* X) {
    float2 t0 = make_float2(x[0].x + x[2].x, x[0].y + x[2].y);
    float2 t1 = make_float2(x[0].x - x[2].x, x[0].y - x[2].y);
    float2 t2 = make_float2(x[1].x + x[3].x, x[1].y + x[3].y);
    float2 t3 = make_float2(x[1].x - x[3].x, x[1].y - x[3].y);
    X[0] = make_float2(t0.x + t2.x, t0.y + t2.y);
    X[2] = make_float2(t0.x - t2.x, t0.y - t2.y);
    if (!INV) {                                  // w4 = -i
        X[1] = make_float2(t1.x + t3.y, t1.y - t3.x);
        X[3] = make_float2(t1.x - t3.y, t1.y + t3.x);
    } else {                                     // w4 = +i
        X[1] = make_float2(t1.x - t3.y, t1.y + t3.x);
        X[3] = make_float2(t1.x + t3.y, t1.y - t3.x);
    }
}

// v * exp(-2*pi*i*k/16) (fwd) / conj (inv); k in {0,1,2,3,4,6,9} (compile-time)
template <bool INV>
__device__ __forceinline__ float2 w16mul(float2 v, int k) {
    constexpr float C = 0.92387953251128674f, S = 0.38268343236508978f,
                    R = 0.70710678118654746f;
    float re = 1.f, im = 0.f;
    switch (k) {
        case 0: return v;
        case 1: re = C;  im = -S; break;
        case 2: re = R;  im = -R; break;
        case 3: re = S;  im = -C; break;
        case 4: re = 0.f; im = -1.f; break;
        case 6: re = -R; im = -R; break;
        case 9: re = -C; im = S;  break;
    }
    if (INV) im = -im;
    return cmul(v, make_float2(re, im));
}

// 16-point DFT in registers: y[k] = sum_n x[n] w16^{nk} (conj for INV).
template <bool INV>
__device__ __forceinline__ void dft16(const float2* x, float2* y) {
    float2 A[4][4];
#pragma unroll
    for (int n0 = 0; n0 < 4; ++n0) {
        float2 in[4] = {x[n0], x[n0 + 4], x[n0 + 8], x[n0 + 12]};
        dft4<INV>(in, A[n0]);
    }
#pragma unroll
    for (int k1 = 0; k1 < 4; ++k1) {
#pragma unroll
        for (int n0 = 1; n0 < 4; ++n0) A[n0][k1] = w16mul<INV>(A[n0][k1], n0 * k1);
        float2 in[4] = {A[0][k1], A[1][k1], A[2][k1], A[3][k1]};
        float2 o[4];
        dft4<INV>(in, o);
#pragma unroll
        for (int k0 = 0; k0 < 4; ++k0) y[k1 + 4 * k0] = o[k0];
    }
}

// Radix-16 "4-step" FFT-256. 16 threads per FFT (sub-index a), each holding
// r[c] = x[a + 16c]. One LDS transpose (padded: t*17+a, group stride 273).
// Exit: r[d] = X[a+16d]. Caller syncs before reusing xg (WAR).
template <bool INV>
__device__ __forceinline__ void fft256_r16(float2* r, float2* xg,
                                           const float2* tw, int a) {
    float2 y[16];
    dft16<INV>(r, y);                         // Y_a[t]
#pragma unroll
    for (int t = 1; t < 16; ++t) {            // outer twiddle w256^{a*t}
        float2 w = tw[a * t];
        if (INV) w.y = -w.y;
        y[t] = cmul(y[t], w);
    }
#pragma unroll
    for (int t = 0; t < 16; ++t) xg[t * 17 + a] = y[t];
    __syncthreads();
#pragma unroll
    for (int aa = 0; aa < 16; ++aa) r[aa] = xg[a * 17 + aa];  // this thread: t'=a
    dft16<INV>(r, y);                         // X[t' + 16d]
#pragma unroll
    for (int i = 0; i < 16; ++i) r[i] = y[i];
}

// K1: X = (mask_l * Z_b)/256, row FFT, write T[b,l,row,:] as half2.
__global__ __launch_bounds__(256) void k_rowfft(
    const float* __restrict__ Zre, const float* __restrict__ Zim,
    const float* __restrict__ Mre, const float* __restrict__ Mim,
    __half2* __restrict__ T) {
    __shared__ float2 tw[256];
    __shared__ float2 xch[4368];              // 16 groups * 273
    int tid = threadIdx.x;
    twinit(tw, tid);
    __syncthreads();

    int g = tid >> 4, a = tid & 15;
    int rowg = blockIdx.x * 16 + g;           // [0, B*L*N)
    int b = rowg >> 12, l = (rowg >> 8) & 15, row = rowg & 255;

    int zbase = (b << 16) + (row << 8);
    int mbase = (l << 16) + (row << 8);
    float2 r[16];
#pragma unroll
    for (int c = 0; c < 16; ++c) {
        int i = a + 16 * c;
        float2 z = make_float2(Zre[zbase + i], Zim[zbase + i]);
        float2 m = make_float2(Mre[mbase + i], Mim[mbase + i]);
        r[c] = cmul(m, z);
    }
    fft256_r16<false>(r, &xch[g * 273], tw, a);

    __half2* outp = T + (((size_t)(b * 16 + l)) << 16) + (row << 8);
#pragma unroll
    for (int d = 0; d < 16; ++d)
        outp[a + 16 * d] = __floats2half2_rn(r[d].x * 0.00390625f,
                                             r[d].y * 0.00390625f);
}

// K2: per (image, 16-col tile): col FFT -> *Ytr -> col IFFT, in place on T.
// Zero LDS traffic between the two FFTs (reg layouts match).
__global__ __launch_bounds__(256) void k_colpass(
    __half2* __restrict__ T, const float* __restrict__ Ytr) {
    __shared__ float2 tw[256];
    __shared__ float2 xch[4368];
    int tid = threadIdx.x;
    twinit(tw, tid);
    __syncthreads();

    int img = blockIdx.x >> 4;
    int c0 = (blockIdx.x & 15) << 4;
    int c = tid & 15, a = tid >> 4;
    size_t base = ((size_t)img << 16) + c0 + c;

    float2 r[16];
#pragma unroll
    for (int cc = 0; cc < 16; ++cc)
        r[cc] = __half22float2(T[base + ((a + 16 * cc) << 8)]);

    fft256_r16<false>(r, &xch[c * 273], tw, a);   // r[d] = X[a + 16d]

#pragma unroll
    for (int d = 0; d < 16; ++d) {
        float y = Ytr[base + ((a + 16 * d) << 8)];
        r[d].x *= y;
        r[d].y *= y;
    }
    __syncthreads();                               // WAR on xch

    fft256_r16<true>(r, &xch[c * 273], tw, a);

#pragma unroll
    for (int d = 0; d < 16; ++d)
        T[base + ((a + 16 * d) << 8)] = __floats2half2_rn(r[d].x, r[d].y);
}

// K3: row IFFT for 4 of 16 l's (blockIdx.y = group); accumulate conj(mask)*v
// in registers; write scaled f32 partial to P[lg][b].
__global__ __launch_bounds__(256) void k_rowifft_acc(
    const __half2* __restrict__ T,
    const float* __restrict__ Mre, const float* __restrict__ Mim,
    float2* __restrict__ P, float scale) {
    __shared__ float2 tw[256];
    __shared__ float2 xch[4368];
    int tid = threadIdx.x;
    twinit(tw, tid);
    __syncthreads();

    int g = tid >> 4, a = tid & 15;
    int rowg = blockIdx.x * 16 + g;           // [0, B*N)
    int b = rowg >> 8, row = rowg & 255;
    int lg = blockIdx.y;                      // l-group [0,4)

    float2 acc[16];
#pragma unroll
    for (int k = 0; k < 16; ++k) acc[k] = make_float2(0.f, 0.f);

#pragma unroll 1
    for (int li = 0; li < 4; ++li) {
        int l = (lg << 2) + li;
        const __half2* src = T + (((size_t)(b * 16 + l)) << 16) + (row << 8);
        float2 r[16];
#pragma unroll
        for (int c = 0; c < 16; ++c) r[c] = __half22float2(src[a + 16 * c]);
        __syncthreads();                      // WAR on xch vs previous iter
        fft256_r16<true>(r, &xch[g * 273], tw, a);
        int mbase = (l << 16) + (row << 8);
#pragma unroll
        for (int d = 0; d < 16; ++d) {
            int i = a + 16 * d;
            float mr = Mre[mbase + i], mi = Mim[mbase + i];
            acc[d].x += mr * r[d].x + mi * r[d].y;   // conj(m) * v
            acc[d].y += mr * r[d].y - mi * r[d].x;
        }
    }

    float2* dst = P + (((size_t)(lg * B_ + b)) << 16) + (row << 8);
#pragma unroll
    for (int d = 0; d < 16; ++d) {
        int i = a + 16 * d;
        dst[i] = make_float2(acc[d].x * scale, acc[d].y * scale);
    }
}

// K3b: ATY = sum over lg of P[lg][b].
__global__ __launch_bounds__(256) void k_sum4(
    const float2* __restrict__ P, float2* __restrict__ ATY) {
    int i = blockIdx.x * 2048 + threadIdx.x;
#pragma unroll
    for (int k = 0; k < 8; ++k) {
        int p = i + (k << 8);                 // [0, B*NN)
        float2 v0 = P[p];
        float2 v1 = P[p + (size_t)B_ * NN];
        float2 v2 = P[p + (size_t)2 * B_ * NN];
        float2 v3 = P[p + (size_t)3 * B_ * NN];
        ATY[p] = make_float2(v0.x + v1.x + v2.x + v3.x,
                             v0.y + v1.y + v2.y + v3.y);
    }
}

// K4a: 5x5 correlation (SAME, zero pad) + bias on re & im, 4-row slices.
__global__ __launch_bounds__(256) void k_conv(
    const float2* __restrict__ ATY, const float* __restrict__ W,
    const float* __restrict__ bptr, float2* __restrict__ Zc,
    float* __restrict__ ssq_part) {
    __shared__ float wsh[25];
    __shared__ float red[256];
    int slice = blockIdx.x & 63;      // 64 slices of 4 rows
    int b = blockIdx.x >> 6;
    int tid = threadIdx.x;
    if (tid < 25) wsh[tid] = W[tid];
    __syncthreads();
    float bias = bptr[0];

    const float2* img = ATY + ((size_t)b << 16);
    float2* zc = Zc + ((size_t)b << 16);
    int row0 = slice << 2;
    float ssq = 0.f;
#pragma unroll 1
    for (int k = 0; k < 4; ++k) {
        int h = row0 + k, w = tid;
        float ar = bias, ai = bias;
#pragma unroll
        for (int kh = 0; kh < 5; ++kh) {
            int hh = h + kh - 2;
            if (hh < 0 || hh > 255) continue;
#pragma unroll
            for (int kw = 0; kw < 5; ++kw) {
                int ww = w + kw - 2;
                if (ww < 0 || ww > 255) continue;
                float wgt = wsh[kh * 5 + kw];
                float2 v = img[(hh << 8) + ww];
                ar = fmaf(v.x, wgt, ar);
                ai = fmaf(v.y, wgt, ai);
            }
        }
        zc[(h << 8) + w] = make_float2(ar, ai);
        ssq = fmaf(ar, ar, fmaf(ai, ai, ssq));
    }
    red[tid] = ssq;
    __syncthreads();
#pragma unroll
    for (int off = 128; off > 0; off >>= 1) {
        if (tid < off) red[tid] += red[tid + off];
        __syncthreads();
    }
    if (tid == 0) ssq_part[blockIdx.x] = red[0];
}

// K4b: sum 64 partials for image b, normalize 4096-pixel slice, write out.
__global__ __launch_bounds__(256) void k_norm(
    const float2* __restrict__ Zc, const float* __restrict__ ssq_part,
    float* __restrict__ out) {
    __shared__ float red[64];
    int slice = blockIdx.x & 15;
    int b = blockIdx.x >> 4;
    int tid = threadIdx.x;
    if (tid < 64) red[tid] = ssq_part[(b << 6) + tid];
    __syncthreads();
    if (tid < 16) red[tid] += red[tid + 16] + red[tid + 32] + red[tid + 48];
    __syncthreads();
    if (tid == 0) {
        float s = 0.f;
#pragma unroll
        for (int i = 0; i < 16; ++i) s += red[i];
        red[0] = s;
    }
    __syncthreads();
    float invf = 1.0f / sqrtf(red[0]);

    const float2* zc = Zc + ((size_t)b << 16);
    float* outRe = out + ((size_t)b << 16);
    float* outIm = out + ((size_t)(B_ + b) << 16);
#pragma unroll
    for (int k = 0; k < 16; ++k) {
        int pix = (slice << 12) + (k << 8) + tid;
        float2 v = zc[pix];
        outRe[pix] = v.x * invf;
        outIm[pix] = v.y * invf;
    }
}

extern "C" void kernel_launch(void* const* d_in, const int* in_sizes, int n_in,
                              void* d_out, int out_size, void* d_ws, size_t ws_size,
                              hipStream_t stream) {
    const float* Zre = (const float*)d_in[0];
    const float* Zim = (const float*)d_in[1];
    const float* Mre = (const float*)d_in[2];
    const float* Mim = (const float*)d_in[3];
    const float* Ytr = (const float*)d_in[4];
    const float* W   = (const float*)d_in[5];
    const float* bia = (const float*)d_in[6];
    float* out = (float*)d_out;

    __half2* T   = (__half2*)d_ws;                       // 128*65536*4B = 33.6 MB
    float2*  P   = (float2*)(T + (size_t)IMGS * NN);     // 4*8*65536*8B = 16.8 MB
    float2*  ATY = P + (size_t)4 * B_ * NN;              // 4.2 MB
    float2*  Zc  = ATY + (size_t)B_ * NN;                // 4.2 MB
    float*   ssq = (float*)(Zc + (size_t)B_ * NN);       // 2 KB
    // total ~59 MB

    // ifft2 (1/65536) * div (M*R = 1048576*174763), compensated by the 1/256
    // prescale folded into K1's T store.
    const float scale = (float)(256.0 / (65536.0 * 1048576.0 * 174763.0));

    k_rowfft<<<dim3(IMGS * N_ / 16), dim3(256), 0, stream>>>(Zre, Zim, Mre, Mim, T);
    k_colpass<<<dim3(IMGS * 16), dim3(256), 0, stream>>>(T, Ytr);
    k_rowifft_acc<<<dim3(B_ * N_ / 16, 4), dim3(256), 0, stream>>>(T, Mre, Mim, P, scale);
    k_sum4<<<dim3(256), dim3(256), 0, stream>>>(P, ATY);
    k_conv<<<dim3(B_ * 64), dim3(256), 0, stream>>>(ATY, W, bia, Zc, ssq);
    k_norm<<<dim3(B_ * 16), dim3(256), 0, stream>>>(Zc, ssq, out);
}

// Round 15
// 157.541 us; speedup vs baseline: 1.5403x; 1.0935x over previous
//
#include <hip/hip_runtime.h>
#include <hip/hip_fp16.h>
#include <math.h>

static constexpr int B_ = 8, L_ = 16, N_ = 256;
static constexpr int NN = N_ * N_;      // 65536
static constexpr int IMGS = B_ * L_;    // 128
static constexpr int LG = 8;            // l-groups in K3

__device__ __forceinline__ float2 cmul(float2 a, float2 b) {
    return make_float2(a.x * b.x - a.y * b.y, a.x * b.y + a.y * b.x);
}

// 16x16-tile layout within an image: every K1/K2/K3 access is base+tid
// (1KB contiguous per load/store instruction group). Verified:
//   K1 store (row fixed, col=a+16d): d*4096 + g*16 + a
//   K2 ld/st (row=a+16cc, col=ct*16+c): cc*4096 + ct*256 + tid
//   K3 ld    (row fixed, col=a+16c):  rt*4096 + c*256 + tid
__device__ __forceinline__ int tidx(int row, int col) {
    return ((row >> 4) << 12) + ((col >> 4) << 8) + ((row & 15) << 4) + (col & 15);
}

// tw[n] = exp(-2*pi*i*n/256), n in [0,256)
__device__ __forceinline__ void twinit(float2* tw, int tid) {
    float ang = -3.14159265358979323846f * (float)tid / 128.0f;
    float s, c;
    sincosf(ang, &s, &c);
    tw[tid] = make_float2(c, s);
}

template <bool INV>
__device__ __forceinline__ void dft4(const float2* x, float2* X) {
    float2 t0 = make_float2(x[0].x + x[2].x, x[0].y + x[2].y);
    float2 t1 = make_float2(x[0].x - x[2].x, x[0].y - x[2].y);
    float2 t2 = make_float2(x[1].x + x[3].x, x[1].y + x[3].y);
    float2 t3 = make_float2(x[1].x - x[3].x, x[1].y - x[3].y);
    X[0] = make_float2(t0.x + t2.x, t0.y + t2.y);
    X[2] = make_float2(t0.x - t2.x, t0.y - t2.y);
    if (!INV) {                                  // w4 = -i
        X[1] = make_float2(t1.x + t3.y, t1.y - t3.x);
        X[3] = make_float2(t1.x - t3.y, t1.y + t3.x);
    } else {                                     // w4 = +i
        X[1] = make_float2(t1.x - t3.y, t1.y + t3.x);
        X[3] = make_float2(t1.x + t3.y, t1.y - t3.x);
    }
}

// v * exp(-2*pi*i*k/16) (fwd) / conj (inv); k in {0,1,2,3,4,6,9}
template <bool INV>
__device__ __forceinline__ float2 w16mul(float2 v, int k) {
    constexpr float C = 0.92387953251128674f, S = 0.38268343236508978f,
                    R = 0.70710678118654746f;
    float re = 1.f, im = 0.f;
    switch (k) {
        case 0: return v;
        case 1: re = C;  im = -S; break;
        case 2: re = R;  im = -R; break;
        case 3: re = S;  im = -C; break;
        case 4: re = 0.f; im = -1.f; break;
        case 6: re = -R; im = -R; break;
        case 9: re = -C; im = S;  break;
    }
    if (INV) im = -im;
    return cmul(v, make_float2(re, im));
}

// 16-point DFT in registers; two radix-4 stages, compile-time twiddles.
template <bool INV>
__device__ __forceinline__ void dft16(const float2* x, float2* y) {
    float2 A[4][4];
#pragma unroll
    for (int n0 = 0; n0 < 4; ++n0) {
        float2 in[4] = {x[n0], x[n0 + 4], x[n0 + 8], x[n0 + 12]};
        dft4<INV>(in, A[n0]);
    }
#pragma unroll
    for (int k1 = 0; k1 < 4; ++k1) {
#pragma unroll
        for (int n0 = 1; n0 < 4; ++n0) A[n0][k1] = w16mul<INV>(A[n0][k1], n0 * k1);
        float2 in[4] = {A[0][k1], A[1][k1], A[2][k1], A[3][k1]};
        float2 o[4];
        dft4<INV>(in, o);
#pragma unroll
        for (int k0 = 0; k0 < 4; ++k0) y[k1 + 4 * k0] = o[k0];
    }
}

// Radix-16 "4-step" FFT-256, 16 threads/FFT, one padded LDS transpose.
// Entry: r[c] = x[a+16c]. Exit: r[d] = X[a+16d]. Caller syncs for WAR on xg.
template <bool INV>
__device__ __forceinline__ void fft256_r16(float2* r, float2* xg,
                                           const float2* tw, int a) {
    float2 y[16];
    dft16<INV>(r, y);
#pragma unroll
    for (int t = 1; t < 16; ++t) {
        float2 w = tw[a * t];
        if (INV) w.y = -w.y;
        y[t] = cmul(y[t], w);
    }
#pragma unroll
    for (int t = 0; t < 16; ++t) xg[t * 17 + a] = y[t];
    __syncthreads();
#pragma unroll
    for (int aa = 0; aa < 16; ++aa) r[aa] = xg[a * 17 + aa];
    dft16<INV>(r, y);
#pragma unroll
    for (int i = 0; i < 16; ++i) r[i] = y[i];
}

// K1: X = (mask_l * Z_b)/256, row FFT, write tiled T as half2.
__global__ __launch_bounds__(256) void k_rowfft(
    const float* __restrict__ Zre, const float* __restrict__ Zim,
    const float* __restrict__ Mre, const float* __restrict__ Mim,
    __half2* __restrict__ T) {
    __shared__ float2 tw[256];
    __shared__ float2 xch[4368];
    int tid = threadIdx.x;
    twinit(tw, tid);
    __syncthreads();

    int g = tid >> 4, a = tid & 15;
    int rowg = blockIdx.x * 16 + g;           // [0, B*L*N)
    int b = rowg >> 12, l = (rowg >> 8) & 15, row = rowg & 255;

    int zbase = (b << 16) + (row << 8);
    int mbase = (l << 16) + (row << 8);
    float2 r[16];
#pragma unroll
    for (int c = 0; c < 16; ++c) {
        int i = a + 16 * c;
        float2 z = make_float2(Zre[zbase + i], Zim[zbase + i]);
        float2 m = make_float2(Mre[mbase + i], Mim[mbase + i]);
        r[c] = cmul(m, z);
    }
    fft256_r16<false>(r, &xch[g * 273], tw, a);

    __half2* outp = T + ((size_t)(b * 16 + l) << 16);
#pragma unroll
    for (int d = 0; d < 16; ++d)
        outp[tidx(row, a + 16 * d)] = __floats2half2_rn(r[d].x * 0.00390625f,
                                                        r[d].y * 0.00390625f);
}

// K2: per (image, 16-col tile): col FFT -> *Ytr -> col IFFT, in place on T.
__global__ __launch_bounds__(256) void k_colpass(
    __half2* __restrict__ T, const float* __restrict__ Ytr) {
    __shared__ float2 tw[256];
    __shared__ float2 xch[4368];
    int tid = threadIdx.x;
    twinit(tw, tid);
    __syncthreads();

    int img = blockIdx.x >> 4;
    int c0 = (blockIdx.x & 15) << 4;
    int c = tid & 15, a = tid >> 4;
    size_t ibase = (size_t)img << 16;
    int colg = c0 + c;

    float2 r[16];
#pragma unroll
    for (int cc = 0; cc < 16; ++cc)
        r[cc] = __half22float2(T[ibase + tidx(a + 16 * cc, colg)]);

    fft256_r16<false>(r, &xch[c * 273], tw, a);   // r[d] = X[a + 16d]

#pragma unroll
    for (int d = 0; d < 16; ++d) {
        float y = Ytr[ibase + ((a + 16 * d) << 8) + colg];
        r[d].x *= y;
        r[d].y *= y;
    }
    __syncthreads();                               // WAR on xch

    fft256_r16<true>(r, &xch[c * 273], tw, a);

#pragma unroll
    for (int d = 0; d < 16; ++d)
        T[ibase + tidx(a + 16 * d, colg)] = __floats2half2_rn(r[d].x, r[d].y);
}

// K3: row IFFT for 2 of 16 l's (blockIdx.y = l-group of 2); accumulate
// conj(mask)*v in regs; store partial * 2^-12 as half2 into P[lg][b].
__global__ __launch_bounds__(256) void k_rowifft_acc(
    const __half2* __restrict__ T,
    const float* __restrict__ Mre, const float* __restrict__ Mim,
    __half2* __restrict__ P) {
    __shared__ float2 tw[256];
    __shared__ float2 xch[4368];
    int tid = threadIdx.x;
    twinit(tw, tid);
    __syncthreads();

    int g = tid >> 4, a = tid & 15;
    int rowg = blockIdx.x * 16 + g;           // [0, B*N)
    int b = rowg >> 8, row = rowg & 255;
    int lg = blockIdx.y;                      // [0, LG)

    float2 acc[16];
#pragma unroll
    for (int k = 0; k < 16; ++k) acc[k] = make_float2(0.f, 0.f);

#pragma unroll 1
    for (int li = 0; li < 16 / LG; ++li) {
        int l = lg * (16 / LG) + li;
        const __half2* src = T + ((size_t)(b * 16 + l) << 16);
        float2 r[16];
#pragma unroll
        for (int c = 0; c < 16; ++c)
            r[c] = __half22float2(src[tidx(row, a + 16 * c)]);
        __syncthreads();                      // WAR on xch vs previous iter
        fft256_r16<true>(r, &xch[g * 273], tw, a);
        int mbase = (l << 16) + (row << 8);
#pragma unroll
        for (int d = 0; d < 16; ++d) {
            int i = a + 16 * d;
            float mr = Mre[mbase + i], mi = Mim[mbase + i];
            acc[d].x += mr * r[d].x + mi * r[d].y;   // conj(m) * v
            acc[d].y += mr * r[d].y - mi * r[d].x;
        }
    }

    const float s1 = 0.000244140625f;         // 2^-12 (keeps fp16 in range)
    __half2* dst = P + (((size_t)(lg * B_ + b)) << 16) + (row << 8);
#pragma unroll
    for (int d = 0; d < 16; ++d) {
        int i = a + 16 * d;
        dst[i] = __floats2half2_rn(acc[d].x * s1, acc[d].y * s1);
    }
}

// K3b: ATY = s2 * sum over lg of P[lg][b]  (f32 out).
__global__ __launch_bounds__(256) void k_sum8(
    const __half2* __restrict__ P, float2* __restrict__ ATY, float s2) {
    int i = blockIdx.x * 2048 + threadIdx.x;
#pragma unroll
    for (int k = 0; k < 8; ++k) {
        int p = i + (k << 8);                 // [0, B*NN)
        float sx = 0.f, sy = 0.f;
#pragma unroll
        for (int lg = 0; lg < LG; ++lg) {
            float2 v = __half22float2(P[p + (size_t)lg * B_ * NN]);
            sx += v.x;
            sy += v.y;
        }
        ATY[p] = make_float2(sx * s2, sy * s2);
    }
}

// K4a: 5x5 correlation (SAME, zero pad) + bias on re & im, 4-row slices.
__global__ __launch_bounds__(256) void k_conv(
    const float2* __restrict__ ATY, const float* __restrict__ W,
    const float* __restrict__ bptr, float2* __restrict__ Zc,
    float* __restrict__ ssq_part) {
    __shared__ float wsh[25];
    __shared__ float red[256];
    int slice = blockIdx.x & 63;
    int b = blockIdx.x >> 6;
    int tid = threadIdx.x;
    if (tid < 25) wsh[tid] = W[tid];
    __syncthreads();
    float bias = bptr[0];

    const float2* img = ATY + ((size_t)b << 16);
    float2* zc = Zc + ((size_t)b << 16);
    int row0 = slice << 2;
    float ssq = 0.f;
#pragma unroll 1
    for (int k = 0; k < 4; ++k) {
        int h = row0 + k, w = tid;
        float ar = bias, ai = bias;
#pragma unroll
        for (int kh = 0; kh < 5; ++kh) {
            int hh = h + kh - 2;
            if (hh < 0 || hh > 255) continue;
#pragma unroll
            for (int kw = 0; kw < 5; ++kw) {
                int ww = w + kw - 2;
                if (ww < 0 || ww > 255) continue;
                float wgt = wsh[kh * 5 + kw];
                float2 v = img[(hh << 8) + ww];
                ar = fmaf(v.x, wgt, ar);
                ai = fmaf(v.y, wgt, ai);
            }
        }
        zc[(h << 8) + w] = make_float2(ar, ai);
        ssq = fmaf(ar, ar, fmaf(ai, ai, ssq));
    }
    red[tid] = ssq;
    __syncthreads();
#pragma unroll
    for (int off = 128; off > 0; off >>= 1) {
        if (tid < off) red[tid] += red[tid + off];
        __syncthreads();
    }
    if (tid == 0) ssq_part[blockIdx.x] = red[0];
}

// K4b: sum 64 partials for image b, normalize 4096-pixel slice, write out.
__global__ __launch_bounds__(256) void k_norm(
    const float2* __restrict__ Zc, const float* __restrict__ ssq_part,
    float* __restrict__ out) {
    __shared__ float red[64];
    int slice = blockIdx.x & 15;
    int b = blockIdx.x >> 4;
    int tid = threadIdx.x;
    if (tid < 64) red[tid] = ssq_part[(b << 6) + tid];
    __syncthreads();
    if (tid < 16) red[tid] += red[tid + 16] + red[tid + 32] + red[tid + 48];
    __syncthreads();
    if (tid == 0) {
        float s = 0.f;
#pragma unroll
        for (int i = 0; i < 16; ++i) s += red[i];
        red[0] = s;
    }
    __syncthreads();
    float invf = 1.0f / sqrtf(red[0]);

    const float2* zc = Zc + ((size_t)b << 16);
    float* outRe = out + ((size_t)b << 16);
    float* outIm = out + ((size_t)(B_ + b) << 16);
#pragma unroll
    for (int k = 0; k < 16; ++k) {
        int pix = (slice << 12) + (k << 8) + tid;
        float2 v = zc[pix];
        outRe[pix] = v.x * invf;
        outIm[pix] = v.y * invf;
    }
}

extern "C" void kernel_launch(void* const* d_in, const int* in_sizes, int n_in,
                              void* d_out, int out_size, void* d_ws, size_t ws_size,
                              hipStream_t stream) {
    const float* Zre = (const float*)d_in[0];
    const float* Zim = (const float*)d_in[1];
    const float* Mre = (const float*)d_in[2];
    const float* Mim = (const float*)d_in[3];
    const float* Ytr = (const float*)d_in[4];
    const float* W   = (const float*)d_in[5];
    const float* bia = (const float*)d_in[6];
    float* out = (float*)d_out;

    __half2* T   = (__half2*)d_ws;                       // 33.6 MB (tiled)
    __half2* P   = T + (size_t)IMGS * NN;                // 8*8*65536*4B = 16.8 MB
    float2*  ATY = (float2*)(P + (size_t)LG * B_ * NN);  // 4.2 MB
    float2*  Zc  = ATY + (size_t)B_ * NN;                // 4.2 MB
    float*   ssq = (float*)(Zc + (size_t)B_ * NN);       // 2 KB

    // Scale bookkeeping: total divisor = 65536 (ifft2) * M*R (1048576*174763).
    // Applied as 2^-8 (K1 store) * 2^-12 (K3 P store) * s2 (sum8):
    // s2 = 2^20 / (65536*1048576*174763) = 1/(65536*174763).
    const float s2 = (float)(1.0 / (65536.0 * 174763.0));

    k_rowfft<<<dim3(IMGS * N_ / 16), dim3(256), 0, stream>>>(Zre, Zim, Mre, Mim, T);
    k_colpass<<<dim3(IMGS * 16), dim3(256), 0, stream>>>(T, Ytr);
    k_rowifft_acc<<<dim3(B_ * N_ / 16, LG), dim3(256), 0, stream>>>(T, Mre, Mim, P);
    k_sum8<<<dim3(256), dim3(256), 0, stream>>>(P, ATY, s2);
    k_conv<<<dim3(B_ * 64), dim3(256), 0, stream>>>(ATY, W, bia, Zc, ssq);
    k_norm<<<dim3(B_ * 16), dim3(256), 0, stream>>>(Zc, ssq, out);
}